// Round 1
// baseline (617.313 us; speedup 1.0000x reference)
//
#include <hip/hip_runtime.h>
#include <hip/hip_bf16.h>

#define OUTF 1024
#define NROWS 65536
#define NBR 4
#define BM 128
#define BN 128
#define BK 64
#define LDT 72  // padded LDS row (bf16 elems): 144B stride, 16B-aligned, conflict-free b128 reads

typedef __attribute__((ext_vector_type(8))) short short8;
typedef __attribute__((ext_vector_type(4))) float f32x4;

__device__ inline unsigned short f2bf(float f) {
    return __builtin_bit_cast(unsigned short, (__bf16)f);
}

// ws int layout: [0..3] counts, [4..7] bases, [8..11] fill positions
__global__ void k_count(const int* __restrict__ feat, int* __restrict__ cnt) {
    __shared__ int lc[NBR];
    int tid = threadIdx.x;
    if (tid < NBR) lc[tid] = 0;
    __syncthreads();
    int r = blockIdx.x * 256 + tid;
    int b = 26 - __clz(feat[r]);  // 32->0, 64->1, 128->2, 256->3
    atomicAdd(&lc[b], 1);
    __syncthreads();
    if (tid < NBR && lc[tid]) atomicAdd(&cnt[tid], lc[tid]);
}

__global__ void k_prefix(int* __restrict__ ws) {
    if (threadIdx.x == 0) {
        int s = 0;
        for (int b = 0; b < NBR; b++) { ws[4 + b] = s; s += ws[b]; ws[8 + b] = 0; }
    }
}

__global__ void k_fill(const int* __restrict__ feat, int* __restrict__ ws,
                       int* __restrict__ rowlist) {
    int tid = threadIdx.x;
    int lane = tid & 63;
    int r = blockIdx.x * 256 + tid;
    int b = 26 - __clz(feat[r]);
    #pragma unroll
    for (int bb = 0; bb < NBR; bb++) {
        unsigned long long mask = __ballot(b == bb);
        int leader = __ffsll((long long)mask) - 1;
        int cntw = __popcll(mask);
        int basepos = 0;
        if (lane == leader) basepos = atomicAdd(&ws[8 + bb], cntw);
        basepos = __shfl(basepos, leader < 0 ? 0 : leader);
        if (b == bb) {
            int prefix = __popcll(mask & ((1ull << lane) - 1ull));
            rowlist[ws[4 + bb] + basepos + prefix] = r;
        }
    }
}

__global__ void k_convw(const float* __restrict__ w, unsigned short* __restrict__ wb) {
    int i = ((int)blockIdx.x * 256 + (int)threadIdx.x) * 4;
    const float4 v = *reinterpret_cast<const float4*>(w + i);
    ushort4 o;
    o.x = f2bf(v.x); o.y = f2bf(v.y); o.z = f2bf(v.z); o.w = f2bf(v.w);
    *reinterpret_cast<ushort4*>(wb + i) = o;
}

template <bool USE_WB>
__global__ __launch_bounds__(256, 3)
void k_gemm(const float* __restrict__ x,
            const unsigned short* __restrict__ wb,
            const float* __restrict__ wf,
            const float* __restrict__ bias,
            const int* __restrict__ ws_i,
            const int* __restrict__ rowlist,
            float* __restrict__ out) {
    __shared__ unsigned short As[BM][LDT];
    __shared__ unsigned short Bs[BN][LDT];

    // map blockIdx.x -> (branch, local tile)
    int t = (int)blockIdx.x;
    int branch = -1, ltile = 0, cnt = 0, rbase = 0;
    #pragma unroll
    for (int b = 0; b < NBR; b++) {
        if (branch < 0) {
            int c = ws_i[b];
            int nt = (c + BM - 1) >> 7;
            if (t < nt) { branch = b; ltile = t; cnt = c; rbase = ws_i[4 + b]; }
            else t -= nt;
        }
    }
    if (branch < 0) return;

    const int tid = threadIdx.x;
    const int lane = tid & 63;
    const int wid = tid >> 6;
    const int wm = (wid & 1) << 6;   // wave row offset (0/64)
    const int wn = (wid >> 1) << 6;  // wave col offset (0/64)
    const int n0 = (int)blockIdx.y * BN;

    // staging: 2 threads per row, 32 elems each
    const int srow = tid >> 1;
    const int scol = (tid & 1) << 5;

    const int gmrow = ltile * BM + srow;
    const int grow = (gmrow < cnt) ? rowlist[rbase + gmrow] : -1;
    const float* xsrc = x + (size_t)(grow < 0 ? 0 : grow) * OUTF + scol;
    const unsigned short* wbsrc = wb + ((size_t)branch << 20) + (size_t)(n0 + srow) * OUTF + scol;
    const float* wfsrc = wf + ((size_t)branch << 20) + (size_t)(n0 + srow) * OUTF + scol;

    f32x4 acc[4][4];
    #pragma unroll
    for (int i = 0; i < 4; i++)
        #pragma unroll
        for (int j = 0; j < 4; j++)
            acc[i][j] = (f32x4){0.f, 0.f, 0.f, 0.f};

    for (int k0 = 0; k0 < OUTF; k0 += BK) {
        {   // stage A: gathered x rows, fp32 -> bf16
            unsigned short* dst = &As[srow][scol];
            if (grow >= 0) {
                const float4* s4 = reinterpret_cast<const float4*>(xsrc + k0);
                #pragma unroll
                for (int i = 0; i < 8; i++) {
                    float4 v = s4[i];
                    ushort4 o;
                    o.x = f2bf(v.x); o.y = f2bf(v.y); o.z = f2bf(v.z); o.w = f2bf(v.w);
                    reinterpret_cast<ushort4*>(dst)[i] = o;
                }
            } else {
                ushort4 z; z.x = z.y = z.z = z.w = 0;
                #pragma unroll
                for (int i = 0; i < 8; i++) reinterpret_cast<ushort4*>(dst)[i] = z;
            }
        }
        {   // stage B: weight tile
            unsigned short* dst = &Bs[srow][scol];
            if (USE_WB) {
                const int4* s4 = reinterpret_cast<const int4*>(wbsrc + k0);
                #pragma unroll
                for (int i = 0; i < 4; i++) reinterpret_cast<int4*>(dst)[i] = s4[i];
            } else {
                const float4* s4 = reinterpret_cast<const float4*>(wfsrc + k0);
                #pragma unroll
                for (int i = 0; i < 8; i++) {
                    float4 v = s4[i];
                    ushort4 o;
                    o.x = f2bf(v.x); o.y = f2bf(v.y); o.z = f2bf(v.z); o.w = f2bf(v.w);
                    reinterpret_cast<ushort4*>(dst)[i] = o;
                }
            }
        }
        __syncthreads();
        #pragma unroll
        for (int kk = 0; kk < BK; kk += 32) {
            const int krd = kk + (lane >> 4) * 8;
            short8 af[4], bf_[4];
            #pragma unroll
            for (int i = 0; i < 4; i++)
                af[i] = *reinterpret_cast<const short8*>(&As[wm + i * 16 + (lane & 15)][krd]);
            #pragma unroll
            for (int i = 0; i < 4; i++)
                bf_[i] = *reinterpret_cast<const short8*>(&Bs[wn + i * 16 + (lane & 15)][krd]);
            #pragma unroll
            for (int i = 0; i < 4; i++)
                #pragma unroll
                for (int j = 0; j < 4; j++)
                    acc[i][j] = __builtin_amdgcn_mfma_f32_16x16x32_bf16(af[i], bf_[j], acc[i][j], 0, 0, 0);
        }
        __syncthreads();
    }

    // epilogue: + bias, scatter to original rows. C/D map: col=lane&15, row=(lane>>4)*4+reg
    const int ccol = lane & 15;
    const int crow = (lane >> 4) << 2;
    float bv[4];
    const float* bp = bias + branch * OUTF + n0 + wn;
    #pragma unroll
    for (int fn = 0; fn < 4; fn++) bv[fn] = bp[fn * 16 + ccol];
    #pragma unroll
    for (int fm = 0; fm < 4; fm++) {
        #pragma unroll
        for (int j = 0; j < 4; j++) {
            int gm = ltile * BM + wm + fm * 16 + crow + j;
            if (gm < cnt) {
                int orow = rowlist[rbase + gm];
                float* orp = out + (size_t)orow * OUTF + n0 + wn;
                #pragma unroll
                for (int fn = 0; fn < 4; fn++)
                    orp[fn * 16 + ccol] = acc[fm][fn][j] + bv[fn];
            }
        }
    }
}

extern "C" void kernel_launch(void* const* d_in, const int* in_sizes, int n_in,
                              void* d_out, int out_size, void* d_ws, size_t ws_size,
                              hipStream_t stream) {
    const float* x = (const float*)d_in[0];
    const int* feat = (const int*)d_in[1];
    const float* w = (const float*)d_in[2];
    const float* bias = (const float*)d_in[3];
    float* out = (float*)d_out;

    char* ws = (char*)d_ws;
    int* ws_i = (int*)ws;
    int* rowlist = (int*)(ws + 256);
    const size_t WB_OFF = (size_t)512 << 10;
    unsigned short* wb = (unsigned short*)(ws + WB_OFF);
    const size_t need_wb = WB_OFF + (size_t)NBR * OUTF * OUTF * 2;

    hipMemsetAsync(ws_i, 0, 64, stream);
    k_count<<<NROWS / 256, 256, 0, stream>>>(feat, ws_i);
    k_prefix<<<1, 64, 0, stream>>>(ws_i);
    k_fill<<<NROWS / 256, 256, 0, stream>>>(feat, ws_i, rowlist);

    dim3 grid(NROWS / BM + NBR, OUTF / BN);
    if (ws_size >= need_wb) {
        k_convw<<<(NBR * OUTF * OUTF) / (256 * 4), 256, 0, stream>>>(w, wb);
        k_gemm<true><<<grid, 256, 0, stream>>>(x, wb, w, bias, ws_i, rowlist, out);
    } else {
        k_gemm<false><<<grid, 256, 0, stream>>>(x, wb, w, bias, ws_i, rowlist, out);
    }
}

// Round 2
// 365.554 us; speedup vs baseline: 1.6887x; 1.6887x over previous
//
#include <hip/hip_runtime.h>
#include <hip/hip_bf16.h>

#define OUTF 1024
#define NROWS 65536
#define NBR 4
#define BM 128
#define BN 128
#define BK 64
#define LDT 72  // fallback-kernel LDS pad

typedef __attribute__((ext_vector_type(8))) short short8;
typedef __attribute__((ext_vector_type(4))) float f32x4;

__device__ inline unsigned short f2bf(float f) {
    return __builtin_bit_cast(unsigned short, (__bf16)f);
}

__device__ inline void gload_lds16(const void* g, void* l) {
    __builtin_amdgcn_global_load_lds(
        (const __attribute__((address_space(1))) void*)g,
        (__attribute__((address_space(3))) void*)l, 16, 0, 0);
}

// ws int layout: [0..3] counts, [4..7] bases, [8..11] fill positions
__global__ void k_count(const int* __restrict__ feat, int* __restrict__ cnt) {
    __shared__ int lc[NBR];
    int tid = threadIdx.x;
    if (tid < NBR) lc[tid] = 0;
    __syncthreads();
    int r = blockIdx.x * 256 + tid;
    int b = 26 - __clz(feat[r]);  // 32->0, 64->1, 128->2, 256->3
    atomicAdd(&lc[b], 1);
    __syncthreads();
    if (tid < NBR && lc[tid]) atomicAdd(&cnt[tid], lc[tid]);
}

__global__ void k_prefix(int* __restrict__ ws) {
    if (threadIdx.x == 0) {
        int s = 0;
        for (int b = 0; b < NBR; b++) { ws[4 + b] = s; s += ws[b]; ws[8 + b] = 0; }
    }
}

__global__ void k_fill(const int* __restrict__ feat, int* __restrict__ ws,
                       int* __restrict__ rowlist) {
    int tid = threadIdx.x;
    int lane = tid & 63;
    int r = blockIdx.x * 256 + tid;
    int b = 26 - __clz(feat[r]);
    #pragma unroll
    for (int bb = 0; bb < NBR; bb++) {
        unsigned long long mask = __ballot(b == bb);
        int leader = __ffsll((long long)mask) - 1;
        int cntw = __popcll(mask);
        int basepos = 0;
        if (lane == leader) basepos = atomicAdd(&ws[8 + bb], cntw);
        basepos = __shfl(basepos, leader < 0 ? 0 : leader);
        if (b == bb) {
            int prefix = __popcll(mask & ((1ull << lane) - 1ull));
            rowlist[ws[4 + bb] + basepos + prefix] = r;
        }
    }
}

__global__ void k_convw(const float* __restrict__ w, unsigned short* __restrict__ wb) {
    int i = ((int)blockIdx.x * 256 + (int)threadIdx.x) * 4;
    const float4 v = *reinterpret_cast<const float4*>(w + i);
    ushort4 o;
    o.x = f2bf(v.x); o.y = f2bf(v.y); o.z = f2bf(v.z); o.w = f2bf(v.w);
    *reinterpret_cast<ushort4*>(wb + i) = o;
}

// gather x rows in rowlist order + convert fp32->bf16 (permuted, branch-contiguous)
__global__ void k_convx(const float* __restrict__ x, const int* __restrict__ rowlist,
                        unsigned short* __restrict__ xb) {
    int idx = ((int)blockIdx.x * 256 + (int)threadIdx.x) << 3;  // bf16 elem index
    int row = idx >> 10;
    int col = idx & (OUTF - 1);
    int src = rowlist[row];
    const float4* s = reinterpret_cast<const float4*>(x + (size_t)src * OUTF + col);
    float4 v0 = s[0], v1 = s[1];
    short8 o;
    o[0] = (short)f2bf(v0.x); o[1] = (short)f2bf(v0.y);
    o[2] = (short)f2bf(v0.z); o[3] = (short)f2bf(v0.w);
    o[4] = (short)f2bf(v1.x); o[5] = (short)f2bf(v1.y);
    o[6] = (short)f2bf(v1.z); o[7] = (short)f2bf(v1.w);
    *reinterpret_cast<short8*>(xb + idx) = o;
}

// m97-structure GEMM: global_load_lds(16B) -> linear LDS [128][64] -> 4x4 MFMA/wave
__global__ __launch_bounds__(256, 3)
void k_gemm2(const unsigned short* __restrict__ xb,
             const unsigned short* __restrict__ wb,
             const float* __restrict__ bias,
             const int* __restrict__ ws_i,
             const int* __restrict__ rowlist,
             float* __restrict__ out) {
    __shared__ unsigned short As[BM][BK];
    __shared__ unsigned short Bs[BN][BK];

    // XCD-chunk swizzle: nwg divisible by 8; each XCD gets a contiguous chunk,
    // M-tile-major so the 8 N-tiles of one A-panel are adjacent (L2 reuse).
    const int nwg = (int)gridDim.x;
    const int d = (int)blockIdx.x;
    const int wg = (d & 7) * (nwg >> 3) + (d >> 3);
    const int mtile = wg >> 3;
    const int ntile = wg & 7;

    // resolve branch segment for this M-tile
    int branch = -1, lt = 0, cnt = 0, rbase = 0;
    int t = mtile;
    #pragma unroll
    for (int b = 0; b < NBR; b++) {
        if (branch < 0) {
            int c = ws_i[b];
            int nt = (c + BM - 1) >> 7;
            if (t < nt) { branch = b; lt = t; cnt = c; rbase = ws_i[4 + b]; }
            else t -= nt;
        }
    }
    if (branch < 0) return;

    const int tid = threadIdx.x;
    const int lane = tid & 63;
    const int w = tid >> 6;
    const int wm = (w & 1) << 6;
    const int wn = (w >> 1) << 6;
    const int n0 = ntile * BN;
    const int row0 = rbase + lt * BM;  // row into permuted xb

    // per-lane global addresses for global_load_lds: lane l covers
    // row (l>>3), 16B chunk (l&7) of each 8-row group
    const int lr = lane >> 3;
    const int lc = (lane & 7) << 3;
    const unsigned short* gA = xb + (size_t)(row0 + w * 32 + lr) * OUTF + lc;
    const unsigned short* gB = wb + ((size_t)branch << 20) + (size_t)(n0 + w * 32 + lr) * OUTF + lc;
    unsigned short* lA = &As[w * 32][0];
    unsigned short* lB = &Bs[w * 32][0];

    f32x4 acc[4][4];
    #pragma unroll
    for (int i = 0; i < 4; i++)
        #pragma unroll
        for (int j = 0; j < 4; j++)
            acc[i][j] = (f32x4){0.f, 0.f, 0.f, 0.f};

    for (int k0 = 0; k0 < OUTF; k0 += BK) {
        #pragma unroll
        for (int i = 0; i < 4; i++) {
            gload_lds16(gA + (size_t)i * 8 * OUTF + k0, lA + i * 8 * BK);
            gload_lds16(gB + (size_t)i * 8 * OUTF + k0, lB + i * 8 * BK);
        }
        __syncthreads();
        #pragma unroll
        for (int kk = 0; kk < BK; kk += 32) {
            const int krd = kk + (lane >> 4) * 8;
            short8 af[4], bfr[4];
            #pragma unroll
            for (int i = 0; i < 4; i++)
                af[i] = *reinterpret_cast<const short8*>(&As[wm + i * 16 + (lane & 15)][krd]);
            #pragma unroll
            for (int i = 0; i < 4; i++)
                bfr[i] = *reinterpret_cast<const short8*>(&Bs[wn + i * 16 + (lane & 15)][krd]);
            #pragma unroll
            for (int i = 0; i < 4; i++)
                #pragma unroll
                for (int j = 0; j < 4; j++)
                    acc[i][j] = __builtin_amdgcn_mfma_f32_16x16x32_bf16(af[i], bfr[j], acc[i][j], 0, 0, 0);
        }
        __syncthreads();
    }

    // epilogue: + bias, scatter to original rows. C/D map: col=lane&15, row=(lane>>4)*4+reg
    const int ccol = lane & 15;
    const int crow = (lane >> 4) << 2;
    float bv[4];
    const float* bp = bias + branch * OUTF + n0 + wn;
    #pragma unroll
    for (int fn = 0; fn < 4; fn++) bv[fn] = bp[fn * 16 + ccol];
    #pragma unroll
    for (int fm = 0; fm < 4; fm++) {
        #pragma unroll
        for (int j = 0; j < 4; j++) {
            int gm = lt * BM + wm + fm * 16 + crow + j;
            if (gm < cnt) {
                int orow = rowlist[rbase + gm];
                float* orp = out + (size_t)orow * OUTF + n0 + wn;
                #pragma unroll
                for (int fn = 0; fn < 4; fn++)
                    orp[fn * 16 + ccol] = acc[fm][fn][j] + bv[fn];
            }
        }
    }
}

// ---------------- fallback (round-1 kernel) if ws is too small ----------------
template <bool USE_WB>
__global__ __launch_bounds__(256, 3)
void k_gemm_fb(const float* __restrict__ x,
               const unsigned short* __restrict__ wb,
               const float* __restrict__ wf,
               const float* __restrict__ bias,
               const int* __restrict__ ws_i,
               const int* __restrict__ rowlist,
               float* __restrict__ out) {
    __shared__ unsigned short As[BM][LDT];
    __shared__ unsigned short Bs[BN][LDT];

    int t = (int)blockIdx.x;
    int branch = -1, ltile = 0, cnt = 0, rbase = 0;
    #pragma unroll
    for (int b = 0; b < NBR; b++) {
        if (branch < 0) {
            int c = ws_i[b];
            int nt = (c + BM - 1) >> 7;
            if (t < nt) { branch = b; ltile = t; cnt = c; rbase = ws_i[4 + b]; }
            else t -= nt;
        }
    }
    if (branch < 0) return;

    const int tid = threadIdx.x;
    const int lane = tid & 63;
    const int wid = tid >> 6;
    const int wm = (wid & 1) << 6;
    const int wn = (wid >> 1) << 6;
    const int n0 = (int)blockIdx.y * BN;

    const int srow = tid >> 1;
    const int scol = (tid & 1) << 5;

    const int gmrow = ltile * BM + srow;
    const int grow = (gmrow < cnt) ? rowlist[rbase + gmrow] : -1;
    const float* xsrc = x + (size_t)(grow < 0 ? 0 : grow) * OUTF + scol;
    const unsigned short* wbsrc = wb + ((size_t)branch << 20) + (size_t)(n0 + srow) * OUTF + scol;
    const float* wfsrc = wf + ((size_t)branch << 20) + (size_t)(n0 + srow) * OUTF + scol;

    f32x4 acc[4][4];
    #pragma unroll
    for (int i = 0; i < 4; i++)
        #pragma unroll
        for (int j = 0; j < 4; j++)
            acc[i][j] = (f32x4){0.f, 0.f, 0.f, 0.f};

    for (int k0 = 0; k0 < OUTF; k0 += BK) {
        {
            unsigned short* dst = &As[srow][scol];
            if (grow >= 0) {
                const float4* s4 = reinterpret_cast<const float4*>(xsrc + k0);
                #pragma unroll
                for (int i = 0; i < 8; i++) {
                    float4 v = s4[i];
                    ushort4 o;
                    o.x = f2bf(v.x); o.y = f2bf(v.y); o.z = f2bf(v.z); o.w = f2bf(v.w);
                    reinterpret_cast<ushort4*>(dst)[i] = o;
                }
            } else {
                ushort4 z; z.x = z.y = z.z = z.w = 0;
                #pragma unroll
                for (int i = 0; i < 8; i++) reinterpret_cast<ushort4*>(dst)[i] = z;
            }
        }
        {
            unsigned short* dst = &Bs[srow][scol];
            if (USE_WB) {
                const int4* s4 = reinterpret_cast<const int4*>(wbsrc + k0);
                #pragma unroll
                for (int i = 0; i < 4; i++) reinterpret_cast<int4*>(dst)[i] = s4[i];
            } else {
                const float4* s4 = reinterpret_cast<const float4*>(wfsrc + k0);
                #pragma unroll
                for (int i = 0; i < 8; i++) {
                    float4 v = s4[i];
                    ushort4 o;
                    o.x = f2bf(v.x); o.y = f2bf(v.y); o.z = f2bf(v.z); o.w = f2bf(v.w);
                    reinterpret_cast<ushort4*>(dst)[i] = o;
                }
            }
        }
        __syncthreads();
        #pragma unroll
        for (int kk = 0; kk < BK; kk += 32) {
            const int krd = kk + (lane >> 4) * 8;
            short8 af[4], bf_[4];
            #pragma unroll
            for (int i = 0; i < 4; i++)
                af[i] = *reinterpret_cast<const short8*>(&As[wm + i * 16 + (lane & 15)][krd]);
            #pragma unroll
            for (int i = 0; i < 4; i++)
                bf_[i] = *reinterpret_cast<const short8*>(&Bs[wn + i * 16 + (lane & 15)][krd]);
            #pragma unroll
            for (int i = 0; i < 4; i++)
                #pragma unroll
                for (int j = 0; j < 4; j++)
                    acc[i][j] = __builtin_amdgcn_mfma_f32_16x16x32_bf16(af[i], bf_[j], acc[i][j], 0, 0, 0);
        }
        __syncthreads();
    }

    const int ccol = lane & 15;
    const int crow = (lane >> 4) << 2;
    float bv[4];
    const float* bp = bias + branch * OUTF + n0 + wn;
    #pragma unroll
    for (int fn = 0; fn < 4; fn++) bv[fn] = bp[fn * 16 + ccol];
    #pragma unroll
    for (int fm = 0; fm < 4; fm++) {
        #pragma unroll
        for (int j = 0; j < 4; j++) {
            int gm = ltile * BM + wm + fm * 16 + crow + j;
            if (gm < cnt) {
                int orow = rowlist[rbase + gm];
                float* orp = out + (size_t)orow * OUTF + n0 + wn;
                #pragma unroll
                for (int fn = 0; fn < 4; fn++)
                    orp[fn * 16 + ccol] = acc[fm][fn][j] + bv[fn];
            }
        }
    }
}

extern "C" void kernel_launch(void* const* d_in, const int* in_sizes, int n_in,
                              void* d_out, int out_size, void* d_ws, size_t ws_size,
                              hipStream_t stream) {
    const float* x = (const float*)d_in[0];
    const int* feat = (const int*)d_in[1];
    const float* w = (const float*)d_in[2];
    const float* bias = (const float*)d_in[3];
    float* out = (float*)d_out;

    char* ws = (char*)d_ws;
    int* ws_i = (int*)ws;
    int* rowlist = (int*)(ws + 256);
    const size_t WB_OFF = (size_t)512 << 10;      // 512 KB
    const size_t XB_OFF = (size_t)16 << 20;       // 16 MB
    unsigned short* wb = (unsigned short*)(ws + WB_OFF);
    unsigned short* xb = (unsigned short*)(ws + XB_OFF);
    const size_t need_wb = WB_OFF + (size_t)NBR * OUTF * OUTF * 2;
    const size_t need_full = XB_OFF + (size_t)(NROWS + 128) * OUTF * 2;

    hipMemsetAsync(ws_i, 0, 64, stream);
    k_count<<<NROWS / 256, 256, 0, stream>>>(feat, ws_i);
    k_prefix<<<1, 64, 0, stream>>>(ws_i);
    k_fill<<<NROWS / 256, 256, 0, stream>>>(feat, ws_i, rowlist);

    if (ws_size >= need_full) {
        k_convw<<<(NBR * OUTF * OUTF) / (256 * 4), 256, 0, stream>>>(w, wb);
        k_convx<<<(NROWS * (OUTF / 8)) / 256, 256, 0, stream>>>(x, rowlist, xb);
        const int nwg = (NROWS / BM + NBR) * (OUTF / BN);  // 516*8 = 4128, %8==0
        k_gemm2<<<nwg, 256, 0, stream>>>(xb, wb, bias, ws_i, rowlist, out);
    } else {
        dim3 grid(NROWS / BM + NBR, OUTF / BN);
        if (ws_size >= need_wb) {
            k_convw<<<(NBR * OUTF * OUTF) / (256 * 4), 256, 0, stream>>>(w, wb);
            k_gemm_fb<true><<<grid, 256, 0, stream>>>(x, wb, w, bias, ws_i, rowlist, out);
        } else {
            k_gemm_fb<false><<<grid, 256, 0, stream>>>(x, wb, w, bias, ws_i, rowlist, out);
        }
    }
}